// Round 1
// baseline (147.374 us; speedup 1.0000x reference)
//
#include <hip/hip_runtime.h>
#include <math.h>

#define NBLOCKS 2048
#define NTHREADS 256

// constants from the reference
#define K_CX 313.0447587080473f
#define K_CY 238.44389626620386f
#define K_RFX (1.0f / 582.6244816773795f)
#define K_RFY (1.0f / 582.6910327098864f)
#define K_EPS 1e-7f

// acc layout (doubles): [0]=n, [1]=sumX, [2]=sumY, [3]=sumZ, [4]=sumLog
__global__ void zero_acc_kernel(double* acc) {
    if (threadIdx.x < 5) acc[threadIdx.x] = 0.0;
}

__global__ __launch_bounds__(NTHREADS) void ddd_reduce_kernel(
        const float* __restrict__ fake, const float* __restrict__ real,
        double* __restrict__ acc, int total4) {
    float sx = 0.f, sy = 0.f, sz = 0.f, sl = 0.f, cnt = 0.f;

    const int stride = gridDim.x * blockDim.x;
    for (int i = blockIdx.x * blockDim.x + threadIdx.x; i < total4; i += stride) {
        float4 f = reinterpret_cast<const float4*>(fake)[i];
        float4 r = reinterpret_cast<const float4*>(real)[i];
        // 640 cols / 4 = 160 float4 per row; rows of 480 per image
        int col4 = (i % 160) * 4;
        int h = (i / 160) % 480;
        float b = ((float)h - K_CY) * K_RFY;

        float fv[4] = {f.x, f.y, f.z, f.w};
        float rv[4] = {r.x, r.y, r.z, r.w};
#pragma unroll
        for (int j = 0; j < 4; ++j) {
            float fj = fv[j], rj = rv[j];
            bool m = (rj > 0.f) && (rj < 1.f) && (fj > 0.f) && (fj < 1.f);
            if (m) {
                float a = ((float)(col4 + j) - K_CX) * K_RFX;
                float xr = rj * a, xf = fj * a;
                if (xr == 0.f) xr = K_EPS;
                if (xf == 0.f) xf = K_EPS;
                float yr = rj * b, yf = fj * b;
                if (yr == 0.f) yr = K_EPS;
                if (yf == 0.f) yf = K_EPS;
                float dx = xr - xf, dy = yr - yf, dz = rj - fj;
                float dl = logf(rj) - logf(fj);  // rj,fj > 0 inside mask
                sx += dx * dx;
                sy += dy * dy;
                sz += dz * dz;
                sl += dl * dl;
                cnt += 1.f;
            }
        }
    }

    // wave64 butterfly-free reduce (shfl_down over width 64)
#pragma unroll
    for (int o = 32; o > 0; o >>= 1) {
        cnt += __shfl_down(cnt, o);
        sx  += __shfl_down(sx, o);
        sy  += __shfl_down(sy, o);
        sz  += __shfl_down(sz, o);
        sl  += __shfl_down(sl, o);
    }

    __shared__ float part[4][5];  // 4 waves per 256-thread block
    int wave = threadIdx.x >> 6;
    int lane = threadIdx.x & 63;
    if (lane == 0) {
        part[wave][0] = cnt;
        part[wave][1] = sx;
        part[wave][2] = sy;
        part[wave][3] = sz;
        part[wave][4] = sl;
    }
    __syncthreads();
    if (threadIdx.x == 0) {
        double t0 = 0, t1 = 0, t2 = 0, t3 = 0, t4 = 0;
#pragma unroll
        for (int w = 0; w < 4; ++w) {
            t0 += (double)part[w][0];
            t1 += (double)part[w][1];
            t2 += (double)part[w][2];
            t3 += (double)part[w][3];
            t4 += (double)part[w][4];
        }
        unsafeAtomicAdd(&acc[0], t0);
        unsafeAtomicAdd(&acc[1], t1);
        unsafeAtomicAdd(&acc[2], t2);
        unsafeAtomicAdd(&acc[3], t3);
        unsafeAtomicAdd(&acc[4], t4);
    }
}

__global__ void finalize_kernel(const double* __restrict__ acc, float* __restrict__ out) {
    double n = acc[0];
    double lx = sqrt(acc[1] / n);
    double ly = sqrt(acc[2] / n);
    double lz = sqrt(acc[3] / n);
    double ll = sqrt(acc[4] / n);
    double loss = 10.0 * (ll + fabs(10.0 * (3.0 - exp(lx) - exp(ly) - exp(lz))));
    out[0] = (float)loss;
}

extern "C" void kernel_launch(void* const* d_in, const int* in_sizes, int n_in,
                              void* d_out, int out_size, void* d_ws, size_t ws_size,
                              hipStream_t stream) {
    const float* fake = (const float*)d_in[0];
    const float* real = (const float*)d_in[1];
    float* out = (float*)d_out;
    double* acc = (double*)d_ws;

    int total = in_sizes[0];          // 64*1*480*640 = 19,660,800
    int total4 = total / 4;           // 4,915,200 float4s

    zero_acc_kernel<<<1, 64, 0, stream>>>(acc);
    ddd_reduce_kernel<<<NBLOCKS, NTHREADS, 0, stream>>>(fake, real, acc, total4);
    finalize_kernel<<<1, 1, 0, stream>>>(acc, out);
}